// Round 1
// baseline (1898.484 us; speedup 1.0000x reference)
//
#include <hip/hip_runtime.h>

#define B_ 64
#define L_ 2048
#define D_ 128
#define LP 2056   // padded rows per batch (3 left, 5 right incl. alignment)
#define PAD 3     // SAME-pad left for W=8

typedef __attribute__((ext_vector_type(8))) short short8;
typedef __attribute__((ext_vector_type(4))) float f32x4;
typedef __attribute__((ext_vector_type(4))) unsigned short us4;

static __device__ __forceinline__ float bf2f(unsigned short u) {
  return __uint_as_float(((unsigned int)u) << 16);
}
static __device__ __forceinline__ unsigned short f2bf(float f) {
  unsigned int x = __float_as_uint(f);
  unsigned int r = (x + 0x7fffu + ((x >> 16) & 1u)) >> 16;  // RNE
  return (unsigned short)r;
}

// ---------------------------------------------------------------------------
// K0: gather tok -> bf16 padded [B,LP,128]; gather bias; transpose weights.
// ---------------------------------------------------------------------------
__global__ __launch_bounds__(256) void k_prep(
    const int* __restrict__ code, const float* __restrict__ E,
    const float* __restrict__ bias_table, const float* __restrict__ Wx,
    const float* __restrict__ c1w, const float* __restrict__ c2w,
    unsigned short* __restrict__ tokpad,
    unsigned short* __restrict__ WxT, unsigned short* __restrict__ c1wT,
    unsigned short* __restrict__ c2wT, float* __restrict__ biasg)
{
  int id = blockIdx.x * 256 + threadIdx.x;
  const int N0 = B_ * LP * 16;            // tokpad in uint4 (8 bf16) chunks
  if (id < N0) {
    int b = id / (LP * 16); int rem = id % (LP * 16);
    int row = rem >> 4, c8 = rem & 15;
    uint4 o = {0u,0u,0u,0u};
    if (row >= PAD && row < PAD + L_) {
      int cd = code[b * L_ + (row - PAD)];
      const float4* e = (const float4*)(E + (size_t)cd * D_ + c8 * 8);
      float4 e0 = e[0], e1 = e[1];
      o.x = f2bf(e0.x) | ((unsigned int)f2bf(e0.y) << 16);
      o.y = f2bf(e0.z) | ((unsigned int)f2bf(e0.w) << 16);
      o.z = f2bf(e1.x) | ((unsigned int)f2bf(e1.y) << 16);
      o.w = f2bf(e1.z) | ((unsigned int)f2bf(e1.w) << 16);
    }
    ((uint4*)tokpad)[id] = o;
    return;
  }
  id -= N0;
  const int N2 = B_ * L_;
  if (id < N2) { biasg[id] = bias_table[code[id]]; return; }
  id -= N2;
  const int N3 = 192 * 128;               // WxT[c][d]
  if (id < N3) { int c = id >> 7, d = id & 127; WxT[id] = f2bf(Wx[d * 192 + c]); return; }
  id -= N3;
  const int N4 = 8 * 64 * 128;            // c1wT[w][c][d]
  if (id < N4) {
    int w = id >> 13, c = (id >> 7) & 63, d = id & 127;
    c1wT[id] = f2bf(c1w[(w * 128 + d) * 64 + c]); return;
  }
  id -= N4;
  const int N5 = 8 * 64 * 64;             // c2wT[w][c][d]
  if (id < N5) {
    int w = id >> 12, c = (id >> 6) & 63, d = id & 63;
    c2wT[id] = f2bf(c2w[(w * 64 + d) * 64 + c]);
  }
}

// ---------------------------------------------------------------------------
// K1: x_proj = tok @ Wx + b_gru[0] -> bf16 TRANSPOSED [B,192,L].
// R10: C tiles bounce through LDS (reusing Bt, same 192x136 shape) so the
// global store is 256 B-contiguous per row — the old direct store scattered
// 8 B pieces at 4 KB stride (6.3M L2 write ops for 50 MB). Values/rounding
// identical: same acc, same f2bf, different store order only.
// ---------------------------------------------------------------------------
__global__ __launch_bounds__(256) void k_xproj(
    const unsigned short* __restrict__ tokpad, const unsigned short* __restrict__ WxT,
    const float* __restrict__ bg, unsigned short* __restrict__ xprojT)
{
  __shared__ __align__(16) unsigned short At[128 * 136];
  __shared__ __align__(16) unsigned short Bt[192 * 136];
  int b = blockIdx.x >> 4;
  int l0 = (blockIdx.x & 15) << 7;
  int tid = threadIdx.x;
  for (int i = tid; i < 128 * 16; i += 256) {
    int row = i >> 4, c8 = i & 15;
    uint4 v = ((const uint4*)tokpad)[(b * LP + PAD + l0 + row) * 16 + c8];
    *((uint4*)&At[row * 136 + c8 * 8]) = v;
  }
  for (int i = tid; i < 192 * 16; i += 256) {
    int row = i >> 4, c8 = i & 15;
    uint4 v = ((const uint4*)WxT)[i];
    *((uint4*)&Bt[row * 136 + c8 * 8]) = v;
  }
  __syncthreads();
  int wave = tid >> 6, lane = tid & 63;
  int m = lane & 15, q = lane >> 4;
  f32x4 acc[2][12];
  #pragma unroll
  for (int mt = 0; mt < 2; ++mt)
    #pragma unroll
    for (int nt = 0; nt < 12; ++nt) acc[mt][nt] = (f32x4){0.f,0.f,0.f,0.f};
  #pragma unroll
  for (int ks = 0; ks < 4; ++ks) {
    int kof = ks * 32 + q * 8;
    short8 a[2], bb[12];
    #pragma unroll
    for (int mt = 0; mt < 2; ++mt)
      a[mt] = *(const short8*)&At[(wave * 32 + mt * 16 + m) * 136 + kof];
    #pragma unroll
    for (int nt = 0; nt < 12; ++nt)
      bb[nt] = *(const short8*)&Bt[(nt * 16 + m) * 136 + kof];
    #pragma unroll
    for (int mt = 0; mt < 2; ++mt)
      #pragma unroll
      for (int nt = 0; nt < 12; ++nt)
        acc[mt][nt] = __builtin_amdgcn_mfma_f32_16x16x32_bf16(a[mt], bb[nt], acc[mt][nt], 0, 0, 0);
  }
  __syncthreads();                        // all MFMA reads of Bt done
  // deposit C (+bias, bf16) transposed into Bt[c][l]  (l = 0..127)
  #pragma unroll
  for (int mt = 0; mt < 2; ++mt) {
    int lrow = wave * 32 + mt * 16 + q * 4;
    #pragma unroll
    for (int nt = 0; nt < 12; ++nt) {
      int c = nt * 16 + m;                 // C col = lane&15
      float b0 = bg[c];
      us4 val;
      val.x = f2bf(acc[mt][nt][0] + b0);
      val.y = f2bf(acc[mt][nt][1] + b0);
      val.z = f2bf(acc[mt][nt][2] + b0);
      val.w = f2bf(acc[mt][nt][3] + b0);
      *((us4*)&Bt[c * 136 + lrow]) = val;
    }
  }
  __syncthreads();
  // coalesced write-out: 16 lanes x 16 B = 256 B contiguous per c-row
  for (int i = tid; i < 192 * 16; i += 256) {
    int row = i >> 4, c8 = i & 15;
    uint4 v = *((const uint4*)&Bt[row * 136 + c8 * 8]);
    ((uint4*)&xprojT[((size_t)b * 192 + row) * L_ + l0])[c8] = v;
  }
}

// ---------------------------------------------------------------------------
// K2 (fused): blocks 0..63 = GRU scan; blocks 64..255 = conv1+conv2 with
// halo recompute (l1 LDS-only, identical bf16 rounding). No cross-block deps.
//
// R11 GRU restructure: the old scan spent ~1180 cyc/step on 2 barriers +
// 2 LDS round trips + 48 broadcast ds_read_b128/step on the shared LDS pipe
// (k_fused counters: MfmaUtil 1.1%, VALUBusy 6.4%, HBM 0.8% — pure latency).
// New: h is REPLICATED lane-distributed in all 3 waves; the h-broadcast for
// the matvec is v_readlane -> v_fma (per-SIMD VALU, no LDS). Exchange is a
// single round trip: wave0 writes z, wave1 writes r, wave2 writes (ah,xh);
// ONE barrier; every wave redundantly finishes tanh + h-update in registers.
// Buffers are parity double-buffered so one barrier/step is race-free.
// FMA order, bias placement, and transcendental formulas are identical to
// the old code -> bitwise-identical h trajectory.
// ---------------------------------------------------------------------------
#define BARRIER() asm volatile("s_waitcnt lgkmcnt(0)\n\ts_barrier" ::: "memory")

#define RLF(V, I) __int_as_float(__builtin_amdgcn_readlane(__float_as_int(V), I))

__global__ __launch_bounds__(192)
__attribute__((amdgpu_waves_per_eu(1, 1)))
void k_fused(
    const unsigned short* __restrict__ xprojT, const float* __restrict__ Wh,
    const float* __restrict__ bg, float* __restrict__ h_t,
    const unsigned short* __restrict__ tokpad,
    const unsigned short* __restrict__ c1wT, const float* __restrict__ c1b,
    const unsigned short* __restrict__ c2wT, const float* __restrict__ c2b,
    unsigned short* __restrict__ c2o)
{
  __shared__ __align__(16) unsigned short pool[39744];
  int bid = blockIdx.x;
  int tid = threadIdx.x;

  if (bid < 64) {
    // ================= GRU scan (R11: readlane matvec, 1 barrier/step) =====
    // zb layout per parity P (256 floats): [0..63]=z, [64..127]=r,
    // [128..255]=(ah,xh) float2 pairs. 2 KB total.
    float* zb = (float*)pool;

    int b = bid;
    int wave = tid >> 6, j = tid & 63;
    int o = wave * 64 + j;                // output column 0..191

#define DECL_W(i) float4 w##i = {Wh[(4*i+0)*192+o], Wh[(4*i+1)*192+o], \
                                 Wh[(4*i+2)*192+o], Wh[(4*i+3)*192+o]};
    DECL_W(0)  DECL_W(1)  DECL_W(2)  DECL_W(3)
    DECL_W(4)  DECL_W(5)  DECL_W(6)  DECL_W(7)
    DECL_W(8)  DECL_W(9)  DECL_W(10) DECL_W(11)
    DECL_W(12) DECL_W(13) DECL_W(14) DECL_W(15)
#undef DECL_W
#define OPAQ(i) asm volatile("" : "+v"(w##i.x), "+v"(w##i.y), "+v"(w##i.z), "+v"(w##i.w));
    OPAQ(0)  OPAQ(1)  OPAQ(2)  OPAQ(3)
    OPAQ(4)  OPAQ(5)  OPAQ(6)  OPAQ(7)
    OPAQ(8)  OPAQ(9)  OPAQ(10) OPAQ(11)
    OPAQ(12) OPAQ(13) OPAQ(14) OPAQ(15)
#undef OPAQ
    float bias = bg[192 + o];             // b_gru[1][o]
    float hreg = 0.f;                     // replicated h[lane] in every wave

    const unsigned short* xc = xprojT + ((size_t)b * 192 + o) * L_;

    uint4 cur0 = ((const uint4*)xc)[0];
    uint4 cur1 = ((const uint4*)xc)[1];

#define MV4(WV, K) \
    a0 = fmaf(RLF(hreg, 4*(K)+0), WV.x, a0); \
    a1 = fmaf(RLF(hreg, 4*(K)+1), WV.y, a1); \
    a2 = fmaf(RLF(hreg, 4*(K)+2), WV.z, a2); \
    a3 = fmaf(RLF(hreg, 4*(K)+3), WV.w, a3);

#define STEP(XU, P) { \
    float a0 = bias, a1 = 0.f, a2 = 0.f, a3 = 0.f; \
    MV4(w0,0)   MV4(w1,1)   MV4(w2,2)   MV4(w3,3)  \
    MV4(w4,4)   MV4(w5,5)   MV4(w6,6)   MV4(w7,7)  \
    MV4(w8,8)   MV4(w9,9)   MV4(w10,10) MV4(w11,11) \
    MV4(w12,12) MV4(w13,13) MV4(w14,14) MV4(w15,15) \
    float s = (a0 + a1) + (a2 + a3); \
    float xv = bf2f((unsigned short)(XU)); \
    if (wave == 0) { \
      zb[(P)*256 + j] = 1.f / (1.f + __expf(-(xv + s))); \
    } else if (wave == 1) { \
      zb[(P)*256 + 64 + j] = 1.f / (1.f + __expf(-(xv + s))); \
    } else { \
      float2 t2; t2.x = s; t2.y = xv; \
      *((float2*)&zb[(P)*256 + 128 + 2*j]) = t2; \
    } \
    BARRIER(); \
    float zg = zb[(P)*256 + j]; \
    float rg = zb[(P)*256 + 64 + j]; \
    float2 ax = *((const float2*)&zb[(P)*256 + 128 + 2*j]); \
    float e2 = __expf(-2.f * (ax.y + rg * ax.x)); \
    float hh = fmaf(2.f, __frcp_rn(1.f + e2), -1.f); \
    hreg = zg * hreg + (1.f - zg) * hh; \
  }

#define STEP8(C) \
    STEP(C.x & 0xffffu, 0) STEP(C.x >> 16, 1) \
    STEP(C.y & 0xffffu, 0) STEP(C.y >> 16, 1) \
    STEP(C.z & 0xffffu, 0) STEP(C.z >> 16, 1) \
    STEP(C.w & 0xffffu, 0) STEP(C.w >> 16, 1)

    for (int t0 = 0; t0 < L_; t0 += 16) {
      int tn = (t0 + 16 < L_) ? t0 + 16 : t0;
      const uint4* pn = (const uint4*)(xc + tn);
      uint4 nxt0 = pn[0];
      uint4 nxt1 = pn[1];
      STEP8(cur0)
      STEP8(cur1)
      cur0 = nxt0; cur1 = nxt1;
    }
#undef STEP8
#undef STEP
#undef MV4
    if (wave == 2) h_t[b * 64 + j] = hreg;
    return;
  }

  // ================= fused conv1+conv2 (halo recompute) =================
  unsigned short* At    = pool;           // 152 x 136 shorts = 41344 B
  unsigned short* l1buf = pool + 20672;   // 144 x 72  shorts = 20736 B
  unsigned short* Bw    = pool + 31040;   //  64 x 136 shorts = 17408 B
  int wv = tid >> 6, lane = tid & 63;
  int m = lane & 15, q = lane >> 4;

  for (int job = bid - 64; job < 1024; job += 192) {
    int b = job >> 4;
    int l0 = (job & 15) << 7;
    __syncthreads();                      // prev job fully consumed
    for (int i = tid; i < 152 * 16; i += 192) {
      int row = i >> 4, c8 = i & 15;
      int p = l0 - 3 + row;
      p = p < 0 ? 0 : (p > 2055 ? 2055 : p);
      *((uint4*)&At[row * 136 + c8 * 8]) = ((const uint4*)tokpad)[(b * LP + p) * 16 + c8];
    }
    // ---- conv1: l1 rows [l0-3, l0+140] (9 M-tiles of 16), K=128 ----
    f32x4 acc[3][4];
    #pragma unroll
    for (int mt = 0; mt < 3; ++mt)
      #pragma unroll
      for (int nt = 0; nt < 4; ++nt) acc[mt][nt] = (f32x4){0.f,0.f,0.f,0.f};
    for (int w8 = 0; w8 < 8; ++w8) {
      __syncthreads();
      for (int i = tid; i < 64 * 16; i += 192) {
        int row = i >> 4, c8 = i & 15;
        *((uint4*)&Bw[row * 136 + c8 * 8]) = ((const uint4*)c1wT)[(w8 * 64 + row) * 16 + c8];
      }
      __syncthreads();
      #pragma unroll
      for (int ks = 0; ks < 4; ++ks) {
        int kof = ks * 32 + q * 8;
        short8 a[3], bb[4];
        #pragma unroll
        for (int mt = 0; mt < 3; ++mt) {
          int tl = wv + 3 * mt;
          a[mt] = *(const short8*)&At[(tl * 16 + m + w8) * 136 + kof];
        }
        #pragma unroll
        for (int nt = 0; nt < 4; ++nt)
          bb[nt] = *(const short8*)&Bw[(nt * 16 + m) * 136 + kof];
        #pragma unroll
        for (int mt = 0; mt < 3; ++mt)
          #pragma unroll
          for (int nt = 0; nt < 4; ++nt)
            acc[mt][nt] = __builtin_amdgcn_mfma_f32_16x16x32_bf16(a[mt], bb[nt], acc[mt][nt], 0, 0, 0);
      }
    }
    #pragma unroll
    for (int mt = 0; mt < 3; ++mt) {
      int tl = wv + 3 * mt;
      #pragma unroll
      for (int nt = 0; nt < 4; ++nt) {
        int c = nt * 16 + m;
        float bs = c1b[c];
        #pragma unroll
        for (int r = 0; r < 4; ++r) {
          float v = fmaxf(acc[mt][nt][r] + bs, 0.f);
          l1buf[(tl * 16 + q * 4 + r) * 72 + c] = f2bf(v);
        }
      }
    }
    __syncthreads();
    for (int i2 = tid; i2 < 135 * 8; i2 += 192) {
      int i = i2 >> 3, c8 = i2 & 7;
      int jrow = l0 - 3 + i;
      if (jrow < 0 || jrow > 2047) {
        uint4 z4 = {0u,0u,0u,0u};
        *((uint4*)&l1buf[i * 72 + c8 * 8]) = z4;
      }
    }
    // ---- conv2: out rows [l0, l0+127] (8 M-tiles), K=64 ----
    f32x4 acc2[3][4];
    #pragma unroll
    for (int mt = 0; mt < 3; ++mt)
      #pragma unroll
      for (int nt = 0; nt < 4; ++nt) acc2[mt][nt] = (f32x4){0.f,0.f,0.f,0.f};
    for (int w8 = 0; w8 < 8; ++w8) {
      __syncthreads();
      for (int i = tid; i < 64 * 8; i += 192) {
        int row = i >> 3, c8 = i & 7;
        *((uint4*)&Bw[row * 72 + c8 * 8]) = ((const uint4*)c2wT)[(w8 * 64 + row) * 8 + c8];
      }
      __syncthreads();
      #pragma unroll
      for (int ks = 0; ks < 2; ++ks) {
        int kof = ks * 32 + q * 8;
        short8 a[3], bb[4];
        #pragma unroll
        for (int mt = 0; mt < 3; ++mt) {
          int tl = wv + 3 * mt;
          if (tl < 8)
            a[mt] = *(const short8*)&l1buf[(tl * 16 + m + w8) * 72 + kof];
        }
        #pragma unroll
        for (int nt = 0; nt < 4; ++nt)
          bb[nt] = *(const short8*)&Bw[(nt * 16 + m) * 72 + kof];
        #pragma unroll
        for (int mt = 0; mt < 3; ++mt) {
          int tl = wv + 3 * mt;
          if (tl < 8)
            #pragma unroll
            for (int nt = 0; nt < 4; ++nt)
              acc2[mt][nt] = __builtin_amdgcn_mfma_f32_16x16x32_bf16(a[mt], bb[nt], acc2[mt][nt], 0, 0, 0);
        }
      }
    }
    #pragma unroll
    for (int mt = 0; mt < 3; ++mt) {
      int tl = wv + 3 * mt;
      if (tl < 8) {
        #pragma unroll
        for (int nt = 0; nt < 4; ++nt) {
          int c = nt * 16 + m;
          float bs = c2b[c];
          #pragma unroll
          for (int r = 0; r < 4; ++r)
            c2o[(size_t)(b * L_ + l0 + tl * 16 + q * 4 + r) * 64 + c] = f2bf(acc2[mt][nt][r] + bs);
        }
      }
    }
  }
}

// ---------------------------------------------------------------------------
// K5: per-batch tail: L2=c2o*h_t -> l2norm -> conv3 -> softmax alpha ->
//     n_hat = sum alpha*tok -> logits = tok.n_hat + bias -> softmax -> out
// ---------------------------------------------------------------------------
__global__ __launch_bounds__(256) void k_final(
    const unsigned short* __restrict__ tokpad, const unsigned short* __restrict__ c2o,
    const float* __restrict__ h_t, const float* __restrict__ c3w,
    const float* __restrict__ c3b, const float* __restrict__ biasg,
    float* __restrict__ out)
{
  __shared__ float Lf[71 * 65];
  __shared__ float a_lds[2048];
  __shared__ float l_lds[2048];
  __shared__ float red[256];
  __shared__ float nred[512];
  __shared__ float nhat[128];
  __shared__ float ht[64];
  __shared__ float c3[512];
  int b = blockIdx.x, tid = threadIdx.x, lane = tid & 63, wave = tid >> 6;
  if (tid < 64) ht[tid] = h_t[b * 64 + tid];
  for (int i = tid; i < 512; i += 256) c3[i] = c3w[i];
  float c3bias = c3b[0];
  __syncthreads();
  // ---- pass 1: a_logits via normalized features + conv3 (tiles of 64 l) ----
  for (int tile = 0; tile < 32; ++tile) {
    int lt = tile << 6;
    for (int i0 = wave; i0 < 71; i0 += 4) {
      int l = lt - 3 + i0;
      float v = 0.f;
      if (l >= 0 && l < L_) v = bf2f(c2o[((size_t)b * L_ + l) * 64 + lane]) * ht[lane];
      float ss = v * v;
      #pragma unroll
      for (int msk = 1; msk < 64; msk <<= 1) ss += __shfl_xor(ss, msk);
      Lf[i0 * 65 + lane] = v * rsqrtf(ss + 1e-12f);
    }
    __syncthreads();
    {
      int u = lane, part = wave;
      float p = 0.f;
      #pragma unroll
      for (int w = 0; w < 8; ++w)
        #pragma unroll
        for (int cc = 0; cc < 16; ++cc) {
          int c = part * 16 + cc;
          p += Lf[(u + w) * 65 + c] * c3[w * 64 + c];
        }
      red[tid] = p;
    }
    __syncthreads();
    if (tid < 64) a_lds[lt + tid] = red[tid] + red[64 + tid] + red[128 + tid] + red[192 + tid] + c3bias;
    __syncthreads();
  }
  // ---- pass 2: softmax alpha over 2048 ----
  {
    float mx = -1e30f;
    for (int i = tid; i < 2048; i += 256) mx = fmaxf(mx, a_lds[i]);
    #pragma unroll
    for (int msk = 1; msk < 64; msk <<= 1) mx = fmaxf(mx, __shfl_xor(mx, msk));
    if (lane == 0) red[wave] = mx;
    __syncthreads();
    mx = fmaxf(fmaxf(red[0], red[1]), fmaxf(red[2], red[3]));
    float sm = 0.f;
    for (int i = tid; i < 2048; i += 256) sm += __expf(a_lds[i] - mx);
    #pragma unroll
    for (int msk = 1; msk < 64; msk <<= 1) sm += __shfl_xor(sm, msk);
    __syncthreads();
    if (lane == 0) red[wave] = sm;
    __syncthreads();
    sm = red[0] + red[1] + red[2] + red[3];
    float inv = 1.f / sm;
    for (int i = tid; i < 2048; i += 256) a_lds[i] = __expf(a_lds[i] - mx) * inv;
    __syncthreads();
  }
  // ---- pass 3: n_hat[128] = sum_l alpha_l * tok[l][:] ----
  {
    int d2 = tid & 63, g = tid >> 6;
    float ax = 0.f, ay = 0.f;
    for (int l = g; l < L_; l += 4) {
      unsigned int uu = *(const unsigned int*)&tokpad[((size_t)b * LP + PAD + l) * 128 + d2 * 2];
      float al = a_lds[l];
      ax += al * bf2f((unsigned short)(uu & 0xffffu));
      ay += al * bf2f((unsigned short)(uu >> 16));
    }
    nred[g * 128 + d2 * 2] = ax;
    nred[g * 128 + d2 * 2 + 1] = ay;
    __syncthreads();
    if (tid < 128) nhat[tid] = nred[tid] + nred[128 + tid] + nred[256 + tid] + nred[384 + tid];
    __syncthreads();
  }
  // ---- pass 4: logits = tok . n_hat + bias ----
  for (int li = 0; li < 8; ++li) {
    int l = li * 256 + tid;
    const uint4* rowp = (const uint4*)&tokpad[((size_t)b * LP + PAD + l) * 128];
    float s = 0.f;
    #pragma unroll
    for (int jj = 0; jj < 16; ++jj) {
      uint4 uu = rowp[jj];
      s += bf2f((unsigned short)(uu.x & 0xffffu)) * nhat[jj*8+0]
         + bf2f((unsigned short)(uu.x >> 16))     * nhat[jj*8+1]
         + bf2f((unsigned short)(uu.y & 0xffffu)) * nhat[jj*8+2]
         + bf2f((unsigned short)(uu.y >> 16))     * nhat[jj*8+3]
         + bf2f((unsigned short)(uu.z & 0xffffu)) * nhat[jj*8+4]
         + bf2f((unsigned short)(uu.z >> 16))     * nhat[jj*8+5]
         + bf2f((unsigned short)(uu.w & 0xffffu)) * nhat[jj*8+6]
         + bf2f((unsigned short)(uu.w >> 16))     * nhat[jj*8+7];
    }
    l_lds[l] = s + biasg[b * L_ + l];
  }
  __syncthreads();
  // ---- pass 5: final softmax -> out ----
  {
    float mx = -1e30f;
    for (int i = tid; i < 2048; i += 256) mx = fmaxf(mx, l_lds[i]);
    #pragma unroll
    for (int msk = 1; msk < 64; msk <<= 1) mx = fmaxf(mx, __shfl_xor(mx, msk));
    __syncthreads();
    if (lane == 0) red[wave] = mx;
    __syncthreads();
    mx = fmaxf(fmaxf(red[0], red[1]), fmaxf(red[2], red[3]));
    float sm = 0.f;
    for (int i = tid; i < 2048; i += 256) sm += __expf(l_lds[i] - mx);
    #pragma unroll
    for (int msk = 1; msk < 64; msk <<= 1) sm += __shfl_xor(sm, msk);
    __syncthreads();
    if (lane == 0) red[wave] = sm;
    __syncthreads();
    sm = red[0] + red[1] + red[2] + red[3];
    float inv = 1.f / sm;
    for (int i = tid; i < 2048; i += 256) out[b * L_ + i] = __expf(l_lds[i] - mx) * inv;
  }
}

// ---------------------------------------------------------------------------
extern "C" void kernel_launch(void* const* d_in, const int* in_sizes, int n_in,
                              void* d_out, int out_size, void* d_ws, size_t ws_size,
                              hipStream_t stream) {
  const int*   code = (const int*)d_in[0];
  const float* E    = (const float*)d_in[1];
  const float* bt   = (const float*)d_in[2];
  const float* Wx   = (const float*)d_in[3];
  const float* Wh   = (const float*)d_in[4];
  const float* bg   = (const float*)d_in[5];
  const float* c1w  = (const float*)d_in[6];
  const float* c1b  = (const float*)d_in[7];
  const float* c2w  = (const float*)d_in[8];
  const float* c2b  = (const float*)d_in[9];
  const float* c3w  = (const float*)d_in[10];
  const float* c3b  = (const float*)d_in[11];
  char* ws = (char*)d_ws;
  unsigned short* tokpad = (unsigned short*)(ws);               // 33,685,504 B
  unsigned short* xprojT = (unsigned short*)(ws + 50528256);    // 50,331,648 B
  unsigned short* c2o    = (unsigned short*)(ws + 100859904);   // 16,777,216 B
  unsigned short* WxT    = (unsigned short*)(ws + 117637120);   //     49,152 B
  unsigned short* c1wT   = (unsigned short*)(ws + 117686272);   //    131,072 B
  unsigned short* c2wT   = (unsigned short*)(ws + 117817344);   //     65,536 B
  float*          htp    = (float*)(ws + 117882880);            //     16,384 B
  float*          biasg  = (float*)(ws + 117899264);            //    524,288 B
  // total ws use: 118,423,552 B

  k_prep <<<9216, 256, 0, stream>>>(code, E, bt, Wx, c1w, c2w, tokpad, WxT, c1wT, c2wT, biasg);
  k_xproj<<<1024, 256, 0, stream>>>(tokpad, WxT, bg, xprojT);
  k_fused<<<256, 192, 0, stream>>>(xprojT, Wh, bg, htp, tokpad, c1wT, c1b, c2wT, c2b, c2o);
  k_final<<<64, 256, 0, stream>>>(tokpad, c2o, htp, c3w, c3b, biasg, (float*)d_out);
}

// Round 2
// 1661.257 us; speedup vs baseline: 1.1428x; 1.1428x over previous
//
#include <hip/hip_runtime.h>

#define B_ 64
#define L_ 2048
#define D_ 128
#define LP 2056   // padded rows per batch (3 left, 5 right incl. alignment)
#define PAD 3     // SAME-pad left for W=8

typedef __attribute__((ext_vector_type(8))) short short8;
typedef __attribute__((ext_vector_type(4))) float f32x4;
typedef __attribute__((ext_vector_type(4))) unsigned short us4;

static __device__ __forceinline__ float bf2f(unsigned short u) {
  return __uint_as_float(((unsigned int)u) << 16);
}
static __device__ __forceinline__ unsigned short f2bf(float f) {
  unsigned int x = __float_as_uint(f);
  unsigned int r = (x + 0x7fffu + ((x >> 16) & 1u)) >> 16;  // RNE
  return (unsigned short)r;
}

// ---------------------------------------------------------------------------
// K0: gather tok -> bf16 padded [B,LP,128]; gather bias; transpose weights.
// ---------------------------------------------------------------------------
__global__ __launch_bounds__(256) void k_prep(
    const int* __restrict__ code, const float* __restrict__ E,
    const float* __restrict__ bias_table, const float* __restrict__ Wx,
    const float* __restrict__ c1w, const float* __restrict__ c2w,
    unsigned short* __restrict__ tokpad,
    unsigned short* __restrict__ WxT, unsigned short* __restrict__ c1wT,
    unsigned short* __restrict__ c2wT, float* __restrict__ biasg)
{
  int id = blockIdx.x * 256 + threadIdx.x;
  const int N0 = B_ * LP * 16;            // tokpad in uint4 (8 bf16) chunks
  if (id < N0) {
    int b = id / (LP * 16); int rem = id % (LP * 16);
    int row = rem >> 4, c8 = rem & 15;
    uint4 o = {0u,0u,0u,0u};
    if (row >= PAD && row < PAD + L_) {
      int cd = code[b * L_ + (row - PAD)];
      const float4* e = (const float4*)(E + (size_t)cd * D_ + c8 * 8);
      float4 e0 = e[0], e1 = e[1];
      o.x = f2bf(e0.x) | ((unsigned int)f2bf(e0.y) << 16);
      o.y = f2bf(e0.z) | ((unsigned int)f2bf(e0.w) << 16);
      o.z = f2bf(e1.x) | ((unsigned int)f2bf(e1.y) << 16);
      o.w = f2bf(e1.z) | ((unsigned int)f2bf(e1.w) << 16);
    }
    ((uint4*)tokpad)[id] = o;
    return;
  }
  id -= N0;
  const int N2 = B_ * L_;
  if (id < N2) { biasg[id] = bias_table[code[id]]; return; }
  id -= N2;
  const int N3 = 192 * 128;               // WxT[c][d]
  if (id < N3) { int c = id >> 7, d = id & 127; WxT[id] = f2bf(Wx[d * 192 + c]); return; }
  id -= N3;
  const int N4 = 8 * 64 * 128;            // c1wT[w][c][d]
  if (id < N4) {
    int w = id >> 13, c = (id >> 7) & 63, d = id & 127;
    c1wT[id] = f2bf(c1w[(w * 128 + d) * 64 + c]); return;
  }
  id -= N4;
  const int N5 = 8 * 64 * 64;             // c2wT[w][c][d]
  if (id < N5) {
    int w = id >> 12, c = (id >> 6) & 63, d = id & 63;
    c2wT[id] = f2bf(c2w[(w * 64 + d) * 64 + c]);
  }
}

// ---------------------------------------------------------------------------
// K1: x_proj = tok @ Wx + b_gru[0] -> bf16 TRANSPOSED [B,192,L].
// R10: C tiles bounce through LDS (reusing Bt, same 192x136 shape) so the
// global store is 256 B-contiguous per row.
// ---------------------------------------------------------------------------
__global__ __launch_bounds__(256) void k_xproj(
    const unsigned short* __restrict__ tokpad, const unsigned short* __restrict__ WxT,
    const float* __restrict__ bg, unsigned short* __restrict__ xprojT)
{
  __shared__ __align__(16) unsigned short At[128 * 136];
  __shared__ __align__(16) unsigned short Bt[192 * 136];
  int b = blockIdx.x >> 4;
  int l0 = (blockIdx.x & 15) << 7;
  int tid = threadIdx.x;
  for (int i = tid; i < 128 * 16; i += 256) {
    int row = i >> 4, c8 = i & 15;
    uint4 v = ((const uint4*)tokpad)[(b * LP + PAD + l0 + row) * 16 + c8];
    *((uint4*)&At[row * 136 + c8 * 8]) = v;
  }
  for (int i = tid; i < 192 * 16; i += 256) {
    int row = i >> 4, c8 = i & 15;
    uint4 v = ((const uint4*)WxT)[i];
    *((uint4*)&Bt[row * 136 + c8 * 8]) = v;
  }
  __syncthreads();
  int wave = tid >> 6, lane = tid & 63;
  int m = lane & 15, q = lane >> 4;
  f32x4 acc[2][12];
  #pragma unroll
  for (int mt = 0; mt < 2; ++mt)
    #pragma unroll
    for (int nt = 0; nt < 12; ++nt) acc[mt][nt] = (f32x4){0.f,0.f,0.f,0.f};
  #pragma unroll
  for (int ks = 0; ks < 4; ++ks) {
    int kof = ks * 32 + q * 8;
    short8 a[2], bb[12];
    #pragma unroll
    for (int mt = 0; mt < 2; ++mt)
      a[mt] = *(const short8*)&At[(wave * 32 + mt * 16 + m) * 136 + kof];
    #pragma unroll
    for (int nt = 0; nt < 12; ++nt)
      bb[nt] = *(const short8*)&Bt[(nt * 16 + m) * 136 + kof];
    #pragma unroll
    for (int mt = 0; mt < 2; ++mt)
      #pragma unroll
      for (int nt = 0; nt < 12; ++nt)
        acc[mt][nt] = __builtin_amdgcn_mfma_f32_16x16x32_bf16(a[mt], bb[nt], acc[mt][nt], 0, 0, 0);
  }
  __syncthreads();                        // all MFMA reads of Bt done
  // deposit C (+bias, bf16) transposed into Bt[c][l]  (l = 0..127)
  #pragma unroll
  for (int mt = 0; mt < 2; ++mt) {
    int lrow = wave * 32 + mt * 16 + q * 4;
    #pragma unroll
    for (int nt = 0; nt < 12; ++nt) {
      int c = nt * 16 + m;                 // C col = lane&15
      float b0 = bg[c];
      us4 val;
      val.x = f2bf(acc[mt][nt][0] + b0);
      val.y = f2bf(acc[mt][nt][1] + b0);
      val.z = f2bf(acc[mt][nt][2] + b0);
      val.w = f2bf(acc[mt][nt][3] + b0);
      *((us4*)&Bt[c * 136 + lrow]) = val;
    }
  }
  __syncthreads();
  // coalesced write-out: 16 lanes x 16 B = 256 B contiguous per c-row
  for (int i = tid; i < 192 * 16; i += 256) {
    int row = i >> 4, c8 = i & 15;
    uint4 v = *((const uint4*)&Bt[row * 136 + c8 * 8]);
    ((uint4*)&xprojT[((size_t)b * 192 + row) * L_ + l0])[c8] = v;
  }
}

// ---------------------------------------------------------------------------
// K2 (fused): blocks 0..63 = GRU scan; blocks 64..255 = conv1+conv2 with
// halo recompute (l1 LDS-only, identical bf16 rounding). No cross-block deps.
//
// R12 GRU: recombine R10's proven broadcast-LDS matvec (16 ds_read_b128
// float4 + 64 fmaf per wave — pipelines well) with R11's single-barrier
// replicated-update exchange. R11's failure: readlane matvec serialized
// (64 readlane->fma dependency stalls, 1540 cyc/step). R10's cost: 2
// barriers + serialized wave-2 section (1180 cyc/step).
// New per step: matvec from OWN-wave h copy -> wave0 writes z, wave1 writes
// r, wave2 writes (s,xh) -> ONE barrier -> every wave redundantly computes
// h_new from the same LDS bits (bitwise identical) -> writes its own h copy
// (wave-local, lgkmcnt-ordered, no barrier). Gate exchange is parity
// double-buffered so one barrier/step is race-free.
// ---------------------------------------------------------------------------
#define BARRIER() asm volatile("s_waitcnt lgkmcnt(0)\n\ts_barrier" ::: "memory")
#define LGKM0()   asm volatile("s_waitcnt lgkmcnt(0)" ::: "memory")

__global__ __launch_bounds__(192)
__attribute__((amdgpu_waves_per_eu(1, 1)))
void k_fused(
    const unsigned short* __restrict__ xprojT, const float* __restrict__ Wh,
    const float* __restrict__ bg, float* __restrict__ h_t,
    const unsigned short* __restrict__ tokpad,
    const unsigned short* __restrict__ c1wT, const float* __restrict__ c1b,
    const unsigned short* __restrict__ c2wT, const float* __restrict__ c2b,
    unsigned short* __restrict__ c2o)
{
  __shared__ __align__(16) unsigned short pool[39744];
  int bid = blockIdx.x;
  int tid = threadIdx.x;

  if (bid < 64) {
    // ================= GRU scan (R12) =================
    // LDS: [0..191] own-wave h copies (3 x 64 f32); [192..703] gate exchange
    // (2 parities x 256 f32: z[64], r[64], (s,xh)[64 float2]).
    float* base = (float*)pool;
    float* hb   = base + (tid >> 6) * 64;   // this wave's private h copy
    float* xch  = base + 192;

    int b = bid;
    int wave = tid >> 6, j = tid & 63;
    int o = wave * 64 + j;                // output column 0..191

#define DECL_W(i) float4 w##i = {Wh[(4*i+0)*192+o], Wh[(4*i+1)*192+o], \
                                 Wh[(4*i+2)*192+o], Wh[(4*i+3)*192+o]};
    DECL_W(0)  DECL_W(1)  DECL_W(2)  DECL_W(3)
    DECL_W(4)  DECL_W(5)  DECL_W(6)  DECL_W(7)
    DECL_W(8)  DECL_W(9)  DECL_W(10) DECL_W(11)
    DECL_W(12) DECL_W(13) DECL_W(14) DECL_W(15)
#undef DECL_W
#define OPAQ(i) asm volatile("" : "+v"(w##i.x), "+v"(w##i.y), "+v"(w##i.z), "+v"(w##i.w));
    OPAQ(0)  OPAQ(1)  OPAQ(2)  OPAQ(3)
    OPAQ(4)  OPAQ(5)  OPAQ(6)  OPAQ(7)
    OPAQ(8)  OPAQ(9)  OPAQ(10) OPAQ(11)
    OPAQ(12) OPAQ(13) OPAQ(14) OPAQ(15)
#undef OPAQ
    float bias = bg[192 + o];             // b_gru[1][o]
    float hreg = 0.f;                     // replicated h[lane j]

    hb[j] = 0.f;                          // init own h copy
    LGKM0();

    const unsigned short* xc = xprojT + ((size_t)b * 192 + o) * L_;
    const float4* hl4 = (const float4*)hb;

    uint4 cur0 = ((const uint4*)xc)[0];
    uint4 cur1 = ((const uint4*)xc)[1];

#define STEP(XU, P) { \
    float a0 = bias, a1 = 0.f, a2 = 0.f, a3 = 0.f; \
    { float4 h4; \
      h4 = hl4[0];  a0 = fmaf(h4.x, w0.x, a0);  a1 = fmaf(h4.y, w0.y, a1);  a2 = fmaf(h4.z, w0.z, a2);  a3 = fmaf(h4.w, w0.w, a3); \
      h4 = hl4[1];  a0 = fmaf(h4.x, w1.x, a0);  a1 = fmaf(h4.y, w1.y, a1);  a2 = fmaf(h4.z, w1.z, a2);  a3 = fmaf(h4.w, w1.w, a3); \
      h4 = hl4[2];  a0 = fmaf(h4.x, w2.x, a0);  a1 = fmaf(h4.y, w2.y, a1);  a2 = fmaf(h4.z, w2.z, a2);  a3 = fmaf(h4.w, w2.w, a3); \
      h4 = hl4[3];  a0 = fmaf(h4.x, w3.x, a0);  a1 = fmaf(h4.y, w3.y, a1);  a2 = fmaf(h4.z, w3.z, a2);  a3 = fmaf(h4.w, w3.w, a3); \
      h4 = hl4[4];  a0 = fmaf(h4.x, w4.x, a0);  a1 = fmaf(h4.y, w4.y, a1);  a2 = fmaf(h4.z, w4.z, a2);  a3 = fmaf(h4.w, w4.w, a3); \
      h4 = hl4[5];  a0 = fmaf(h4.x, w5.x, a0);  a1 = fmaf(h4.y, w5.y, a1);  a2 = fmaf(h4.z, w5.z, a2);  a3 = fmaf(h4.w, w5.w, a3); \
      h4 = hl4[6];  a0 = fmaf(h4.x, w6.x, a0);  a1 = fmaf(h4.y, w6.y, a1);  a2 = fmaf(h4.z, w6.z, a2);  a3 = fmaf(h4.w, w6.w, a3); \
      h4 = hl4[7];  a0 = fmaf(h4.x, w7.x, a0);  a1 = fmaf(h4.y, w7.y, a1);  a2 = fmaf(h4.z, w7.z, a2);  a3 = fmaf(h4.w, w7.w, a3); \
      h4 = hl4[8];  a0 = fmaf(h4.x, w8.x, a0);  a1 = fmaf(h4.y, w8.y, a1);  a2 = fmaf(h4.z, w8.z, a2);  a3 = fmaf(h4.w, w8.w, a3); \
      h4 = hl4[9];  a0 = fmaf(h4.x, w9.x, a0);  a1 = fmaf(h4.y, w9.y, a1);  a2 = fmaf(h4.z, w9.z, a2);  a3 = fmaf(h4.w, w9.w, a3); \
      h4 = hl4[10]; a0 = fmaf(h4.x, w10.x, a0); a1 = fmaf(h4.y, w10.y, a1); a2 = fmaf(h4.z, w10.z, a2); a3 = fmaf(h4.w, w10.w, a3); \
      h4 = hl4[11]; a0 = fmaf(h4.x, w11.x, a0); a1 = fmaf(h4.y, w11.y, a1); a2 = fmaf(h4.z, w11.z, a2); a3 = fmaf(h4.w, w11.w, a3); \
      h4 = hl4[12]; a0 = fmaf(h4.x, w12.x, a0); a1 = fmaf(h4.y, w12.y, a1); a2 = fmaf(h4.z, w12.z, a2); a3 = fmaf(h4.w, w12.w, a3); \
      h4 = hl4[13]; a0 = fmaf(h4.x, w13.x, a0); a1 = fmaf(h4.y, w13.y, a1); a2 = fmaf(h4.z, w13.z, a2); a3 = fmaf(h4.w, w13.w, a3); \
      h4 = hl4[14]; a0 = fmaf(h4.x, w14.x, a0); a1 = fmaf(h4.y, w14.y, a1); a2 = fmaf(h4.z, w14.z, a2); a3 = fmaf(h4.w, w14.w, a3); \
      h4 = hl4[15]; a0 = fmaf(h4.x, w15.x, a0); a1 = fmaf(h4.y, w15.y, a1); a2 = fmaf(h4.z, w15.z, a2); a3 = fmaf(h4.w, w15.w, a3); } \
    float s = (a0 + a1) + (a2 + a3); \
    float xv = bf2f((unsigned short)(XU)); \
    if (wave == 0) { \
      xch[(P)*256 + j] = 1.f / (1.f + __expf(-(xv + s))); \
    } else if (wave == 1) { \
      xch[(P)*256 + 64 + j] = 1.f / (1.f + __expf(-(xv + s))); \
    } else { \
      float2 t2; t2.x = s; t2.y = xv; \
      *((float2*)&xch[(P)*256 + 128 + 2*j]) = t2; \
    } \
    BARRIER(); \
    float zg = xch[(P)*256 + j]; \
    float rg = xch[(P)*256 + 64 + j]; \
    float2 ax = *((const float2*)&xch[(P)*256 + 128 + 2*j]); \
    float e2 = __expf(-2.f * (ax.y + rg * ax.x)); \
    float hh = fmaf(2.f, __frcp_rn(1.f + e2), -1.f); \
    hreg = zg * hreg + (1.f - zg) * hh; \
    hb[j] = hreg; \
    LGKM0(); \
  }

#define STEP8(C) \
    STEP(C.x & 0xffffu, 0) STEP(C.x >> 16, 1) \
    STEP(C.y & 0xffffu, 0) STEP(C.y >> 16, 1) \
    STEP(C.z & 0xffffu, 0) STEP(C.z >> 16, 1) \
    STEP(C.w & 0xffffu, 0) STEP(C.w >> 16, 1)

    for (int t0 = 0; t0 < L_; t0 += 16) {
      int tn = (t0 + 16 < L_) ? t0 + 16 : t0;
      const uint4* pn = (const uint4*)(xc + tn);
      uint4 nxt0 = pn[0];
      uint4 nxt1 = pn[1];
      STEP8(cur0)
      STEP8(cur1)
      cur0 = nxt0; cur1 = nxt1;
    }
#undef STEP8
#undef STEP
    if (wave == 2) h_t[b * 64 + j] = hreg;
    return;
  }

  // ================= fused conv1+conv2 (halo recompute) =================
  unsigned short* At    = pool;           // 152 x 136 shorts = 41344 B
  unsigned short* l1buf = pool + 20672;   // 144 x 72  shorts = 20736 B
  unsigned short* Bw    = pool + 31040;   //  64 x 136 shorts = 17408 B
  int wv = tid >> 6, lane = tid & 63;
  int m = lane & 15, q = lane >> 4;

  for (int job = bid - 64; job < 1024; job += 192) {
    int b = job >> 4;
    int l0 = (job & 15) << 7;
    __syncthreads();                      // prev job fully consumed
    for (int i = tid; i < 152 * 16; i += 192) {
      int row = i >> 4, c8 = i & 15;
      int p = l0 - 3 + row;
      p = p < 0 ? 0 : (p > 2055 ? 2055 : p);
      *((uint4*)&At[row * 136 + c8 * 8]) = ((const uint4*)tokpad)[(b * LP + p) * 16 + c8];
    }
    // ---- conv1: l1 rows [l0-3, l0+140] (9 M-tiles of 16), K=128 ----
    f32x4 acc[3][4];
    #pragma unroll
    for (int mt = 0; mt < 3; ++mt)
      #pragma unroll
      for (int nt = 0; nt < 4; ++nt) acc[mt][nt] = (f32x4){0.f,0.f,0.f,0.f};
    for (int w8 = 0; w8 < 8; ++w8) {
      __syncthreads();
      for (int i = tid; i < 64 * 16; i += 192) {
        int row = i >> 4, c8 = i & 15;
        *((uint4*)&Bw[row * 136 + c8 * 8]) = ((const uint4*)c1wT)[(w8 * 64 + row) * 16 + c8];
      }
      __syncthreads();
      #pragma unroll
      for (int ks = 0; ks < 4; ++ks) {
        int kof = ks * 32 + q * 8;
        short8 a[3], bb[4];
        #pragma unroll
        for (int mt = 0; mt < 3; ++mt) {
          int tl = wv + 3 * mt;
          a[mt] = *(const short8*)&At[(tl * 16 + m + w8) * 136 + kof];
        }
        #pragma unroll
        for (int nt = 0; nt < 4; ++nt)
          bb[nt] = *(const short8*)&Bw[(nt * 16 + m) * 136 + kof];
        #pragma unroll
        for (int mt = 0; mt < 3; ++mt)
          #pragma unroll
          for (int nt = 0; nt < 4; ++nt)
            acc[mt][nt] = __builtin_amdgcn_mfma_f32_16x16x32_bf16(a[mt], bb[nt], acc[mt][nt], 0, 0, 0);
      }
    }
    #pragma unroll
    for (int mt = 0; mt < 3; ++mt) {
      int tl = wv + 3 * mt;
      #pragma unroll
      for (int nt = 0; nt < 4; ++nt) {
        int c = nt * 16 + m;
        float bs = c1b[c];
        #pragma unroll
        for (int r = 0; r < 4; ++r) {
          float v = fmaxf(acc[mt][nt][r] + bs, 0.f);
          l1buf[(tl * 16 + q * 4 + r) * 72 + c] = f2bf(v);
        }
      }
    }
    __syncthreads();
    for (int i2 = tid; i2 < 135 * 8; i2 += 192) {
      int i = i2 >> 3, c8 = i2 & 7;
      int jrow = l0 - 3 + i;
      if (jrow < 0 || jrow > 2047) {
        uint4 z4 = {0u,0u,0u,0u};
        *((uint4*)&l1buf[i * 72 + c8 * 8]) = z4;
      }
    }
    // ---- conv2: out rows [l0, l0+127] (8 M-tiles), K=64 ----
    f32x4 acc2[3][4];
    #pragma unroll
    for (int mt = 0; mt < 3; ++mt)
      #pragma unroll
      for (int nt = 0; nt < 4; ++nt) acc2[mt][nt] = (f32x4){0.f,0.f,0.f,0.f};
    for (int w8 = 0; w8 < 8; ++w8) {
      __syncthreads();
      for (int i = tid; i < 64 * 8; i += 192) {
        int row = i >> 3, c8 = i & 7;
        *((uint4*)&Bw[row * 72 + c8 * 8]) = ((const uint4*)c2wT)[(w8 * 64 + row) * 8 + c8];
      }
      __syncthreads();
      #pragma unroll
      for (int ks = 0; ks < 2; ++ks) {
        int kof = ks * 32 + q * 8;
        short8 a[3], bb[4];
        #pragma unroll
        for (int mt = 0; mt < 3; ++mt) {
          int tl = wv + 3 * mt;
          if (tl < 8)
            a[mt] = *(const short8*)&l1buf[(tl * 16 + m + w8) * 72 + kof];
        }
        #pragma unroll
        for (int nt = 0; nt < 4; ++nt)
          bb[nt] = *(const short8*)&Bw[(nt * 16 + m) * 72 + kof];
        #pragma unroll
        for (int mt = 0; mt < 3; ++mt) {
          int tl = wv + 3 * mt;
          if (tl < 8)
            #pragma unroll
            for (int nt = 0; nt < 4; ++nt)
              acc2[mt][nt] = __builtin_amdgcn_mfma_f32_16x16x32_bf16(a[mt], bb[nt], acc2[mt][nt], 0, 0, 0);
        }
      }
    }
    #pragma unroll
    for (int mt = 0; mt < 3; ++mt) {
      int tl = wv + 3 * mt;
      if (tl < 8) {
        #pragma unroll
        for (int nt = 0; nt < 4; ++nt) {
          int c = nt * 16 + m;
          float bs = c2b[c];
          #pragma unroll
          for (int r = 0; r < 4; ++r)
            c2o[(size_t)(b * L_ + l0 + tl * 16 + q * 4 + r) * 64 + c] = f2bf(acc2[mt][nt][r] + bs);
        }
      }
    }
  }
}

// ---------------------------------------------------------------------------
// K5: per-batch tail: L2=c2o*h_t -> l2norm -> conv3 -> softmax alpha ->
//     n_hat = sum alpha*tok -> logits = tok.n_hat + bias -> softmax -> out
// ---------------------------------------------------------------------------
__global__ __launch_bounds__(256) void k_final(
    const unsigned short* __restrict__ tokpad, const unsigned short* __restrict__ c2o,
    const float* __restrict__ h_t, const float* __restrict__ c3w,
    const float* __restrict__ c3b, const float* __restrict__ biasg,
    float* __restrict__ out)
{
  __shared__ float Lf[71 * 65];
  __shared__ float a_lds[2048];
  __shared__ float l_lds[2048];
  __shared__ float red[256];
  __shared__ float nred[512];
  __shared__ float nhat[128];
  __shared__ float ht[64];
  __shared__ float c3[512];
  int b = blockIdx.x, tid = threadIdx.x, lane = tid & 63, wave = tid >> 6;
  if (tid < 64) ht[tid] = h_t[b * 64 + tid];
  for (int i = tid; i < 512; i += 256) c3[i] = c3w[i];
  float c3bias = c3b[0];
  __syncthreads();
  // ---- pass 1: a_logits via normalized features + conv3 (tiles of 64 l) ----
  for (int tile = 0; tile < 32; ++tile) {
    int lt = tile << 6;
    for (int i0 = wave; i0 < 71; i0 += 4) {
      int l = lt - 3 + i0;
      float v = 0.f;
      if (l >= 0 && l < L_) v = bf2f(c2o[((size_t)b * L_ + l) * 64 + lane]) * ht[lane];
      float ss = v * v;
      #pragma unroll
      for (int msk = 1; msk < 64; msk <<= 1) ss += __shfl_xor(ss, msk);
      Lf[i0 * 65 + lane] = v * rsqrtf(ss + 1e-12f);
    }
    __syncthreads();
    {
      int u = lane, part = wave;
      float p = 0.f;
      #pragma unroll
      for (int w = 0; w < 8; ++w)
        #pragma unroll
        for (int cc = 0; cc < 16; ++cc) {
          int c = part * 16 + cc;
          p += Lf[(u + w) * 65 + c] * c3[w * 64 + c];
        }
      red[tid] = p;
    }
    __syncthreads();
    if (tid < 64) a_lds[lt + tid] = red[tid] + red[64 + tid] + red[128 + tid] + red[192 + tid] + c3bias;
    __syncthreads();
  }
  // ---- pass 2: softmax alpha over 2048 ----
  {
    float mx = -1e30f;
    for (int i = tid; i < 2048; i += 256) mx = fmaxf(mx, a_lds[i]);
    #pragma unroll
    for (int msk = 1; msk < 64; msk <<= 1) mx = fmaxf(mx, __shfl_xor(mx, msk));
    if (lane == 0) red[wave] = mx;
    __syncthreads();
    mx = fmaxf(fmaxf(red[0], red[1]), fmaxf(red[2], red[3]));
    float sm = 0.f;
    for (int i = tid; i < 2048; i += 256) sm += __expf(a_lds[i] - mx);
    #pragma unroll
    for (int msk = 1; msk < 64; msk <<= 1) sm += __shfl_xor(sm, msk);
    __syncthreads();
    if (lane == 0) red[wave] = sm;
    __syncthreads();
    sm = red[0] + red[1] + red[2] + red[3];
    float inv = 1.f / sm;
    for (int i = tid; i < 2048; i += 256) a_lds[i] = __expf(a_lds[i] - mx) * inv;
    __syncthreads();
  }
  // ---- pass 3: n_hat[128] = sum_l alpha_l * tok[l][:] ----
  {
    int d2 = tid & 63, g = tid >> 6;
    float ax = 0.f, ay = 0.f;
    for (int l = g; l < L_; l += 4) {
      unsigned int uu = *(const unsigned int*)&tokpad[((size_t)b * LP + PAD + l) * 128 + d2 * 2];
      float al = a_lds[l];
      ax += al * bf2f((unsigned short)(uu & 0xffffu));
      ay += al * bf2f((unsigned short)(uu >> 16));
    }
    nred[g * 128 + d2 * 2] = ax;
    nred[g * 128 + d2 * 2 + 1] = ay;
    __syncthreads();
    if (tid < 128) nhat[tid] = nred[tid] + nred[128 + tid] + nred[256 + tid] + nred[384 + tid];
    __syncthreads();
  }
  // ---- pass 4: logits = tok . n_hat + bias ----
  for (int li = 0; li < 8; ++li) {
    int l = li * 256 + tid;
    const uint4* rowp = (const uint4*)&tokpad[((size_t)b * LP + PAD + l) * 128];
    float s = 0.f;
    #pragma unroll
    for (int jj = 0; jj < 16; ++jj) {
      uint4 uu = rowp[jj];
      s += bf2f((unsigned short)(uu.x & 0xffffu)) * nhat[jj*8+0]
         + bf2f((unsigned short)(uu.x >> 16))     * nhat[jj*8+1]
         + bf2f((unsigned short)(uu.y & 0xffffu)) * nhat[jj*8+2]
         + bf2f((unsigned short)(uu.y >> 16))     * nhat[jj*8+3]
         + bf2f((unsigned short)(uu.z & 0xffffu)) * nhat[jj*8+4]
         + bf2f((unsigned short)(uu.z >> 16))     * nhat[jj*8+5]
         + bf2f((unsigned short)(uu.w & 0xffffu)) * nhat[jj*8+6]
         + bf2f((unsigned short)(uu.w >> 16))     * nhat[jj*8+7];
    }
    l_lds[l] = s + biasg[b * L_ + l];
  }
  __syncthreads();
  // ---- pass 5: final softmax -> out ----
  {
    float mx = -1e30f;
    for (int i = tid; i < 2048; i += 256) mx = fmaxf(mx, l_lds[i]);
    #pragma unroll
    for (int msk = 1; msk < 64; msk <<= 1) mx = fmaxf(mx, __shfl_xor(mx, msk));
    __syncthreads();
    if (lane == 0) red[wave] = mx;
    __syncthreads();
    mx = fmaxf(fmaxf(red[0], red[1]), fmaxf(red[2], red[3]));
    float sm = 0.f;
    for (int i = tid; i < 2048; i += 256) sm += __expf(l_lds[i] - mx);
    #pragma unroll
    for (int msk = 1; msk < 64; msk <<= 1) sm += __shfl_xor(sm, msk);
    __syncthreads();
    if (lane == 0) red[wave] = sm;
    __syncthreads();
    sm = red[0] + red[1] + red[2] + red[3];
    float inv = 1.f / sm;
    for (int i = tid; i < 2048; i += 256) out[b * L_ + i] = __expf(l_lds[i] - mx) * inv;
  }
}

// ---------------------------------------------------------------------------
extern "C" void kernel_launch(void* const* d_in, const int* in_sizes, int n_in,
                              void* d_out, int out_size, void* d_ws, size_t ws_size,
                              hipStream_t stream) {
  const int*   code = (const int*)d_in[0];
  const float* E    = (const float*)d_in[1];
  const float* bt   = (const float*)d_in[2];
  const float* Wx   = (const float*)d_in[3];
  const float* Wh   = (const float*)d_in[4];
  const float* bg   = (const float*)d_in[5];
  const float* c1w  = (const float*)d_in[6];
  const float* c1b  = (const float*)d_in[7];
  const float* c2w  = (const float*)d_in[8];
  const float* c2b  = (const float*)d_in[9];
  const float* c3w  = (const float*)d_in[10];
  const float* c3b  = (const float*)d_in[11];
  char* ws = (char*)d_ws;
  unsigned short* tokpad = (unsigned short*)(ws);               // 33,685,504 B
  unsigned short* xprojT = (unsigned short*)(ws + 50528256);    // 50,331,648 B
  unsigned short* c2o    = (unsigned short*)(ws + 100859904);   // 16,777,216 B
  unsigned short* WxT    = (unsigned short*)(ws + 117637120);   //     49,152 B
  unsigned short* c1wT   = (unsigned short*)(ws + 117686272);   //    131,072 B
  unsigned short* c2wT   = (unsigned short*)(ws + 117817344);   //     65,536 B
  float*          htp    = (float*)(ws + 117882880);            //     16,384 B
  float*          biasg  = (float*)(ws + 117899264);            //    524,288 B
  // total ws use: 118,423,552 B

  k_prep <<<9216, 256, 0, stream>>>(code, E, bt, Wx, c1w, c2w, tokpad, WxT, c1wT, c2wT, biasg);
  k_xproj<<<1024, 256, 0, stream>>>(tokpad, WxT, bg, xprojT);
  k_fused<<<256, 192, 0, stream>>>(xprojT, Wh, bg, htp, tokpad, c1wT, c1b, c2wT, c2b, c2o);
  k_final<<<64, 256, 0, stream>>>(tokpad, c2o, htp, c3w, c3b, biasg, (float*)d_out);
}